// Round 1
// baseline (1321.196 us; speedup 1.0000x reference)
//
#include <hip/hip_runtime.h>
#include <math.h>

#define BN_EPS 1e-5f

// ---------------- degree / feature / norm precompute ----------------

__global__ __launch_bounds__(256) void deg_kernel(const int* __restrict__ row, const int* __restrict__ col,
                                                  float* __restrict__ deg_src, float* __restrict__ deg_dst, int E) {
    int e = blockIdx.x * 256 + threadIdx.x;
    if (e < E) {
        atomicAdd(&deg_src[row[e]], 1.0f);
        atomicAdd(&deg_dst[col[e]], 1.0f);
    }
}

__global__ __launch_bounds__(256) void dinv_kernel(float* __restrict__ deg_dst, int N) {
    int n = blockIdx.x * 256 + threadIdx.x;
    if (n < N) {
        float d = deg_dst[n];
        deg_dst[n] = (d > 0.0f) ? rsqrtf(d) : 0.0f;   // deg>0 -> max(deg,1)==deg
    }
}

__global__ __launch_bounds__(256) void initx_kernel(const float* __restrict__ emb, const float* __restrict__ deg_src,
                                                    float* __restrict__ x, int N) {
    int idx = blockIdx.x * 256 + threadIdx.x;
    if (idx < N * 128) {
        int n = idx >> 7, c = idx & 127;
        x[idx] = (c < 127) ? emb[(size_t)n * 127 + c] : logf(deg_src[n] + 1.0f);
    }
}

__global__ __launch_bounds__(256) void norm_kernel(const int* __restrict__ row, const int* __restrict__ col,
                                                   const float* __restrict__ dinv, float* __restrict__ norm, int E) {
    int e = blockIdx.x * 256 + threadIdx.x;
    if (e < E) norm[e] = dinv[row[e]] * dinv[col[e]];
}

// ---------------- GEMM: H[N,128] = X[N,128] @ W[128,128] (f32, vector ALU) ----------------
// 128-row x 128-col tile per block, 256 threads, 8x8 register micro-tile, k-chunks of 32.

__global__ __launch_bounds__(256) void gemm_kernel(const float* __restrict__ X, const float* __restrict__ W,
                                                   float* __restrict__ H, int N) {
    __shared__ float xs[128][36];   // padded: 16B-aligned rows, conflict-light
    __shared__ float wsh[32][132];
    const int tid = threadIdx.x;
    const int tr = tid & 15;        // row group: rows tr + 16*j
    const int tc = tid >> 4;        // col group: cols tc*8 .. tc*8+7
    const int row0 = blockIdx.x * 128;

    float acc[8][8];
#pragma unroll
    for (int a = 0; a < 8; ++a)
#pragma unroll
        for (int b = 0; b < 8; ++b) acc[a][b] = 0.0f;

    for (int kc = 0; kc < 128; kc += 32) {
        // load X tile: 128 rows x 32 k = 1024 float4, 4 per thread
#pragma unroll
        for (int t = 0; t < 4; ++t) {
            int f = tid + t * 256;
            int r = f >> 3;             // 0..127
            int kq = (f & 7) * 4;       // 0,4,..,28
            int gr = row0 + r;
            float4 v = make_float4(0.f, 0.f, 0.f, 0.f);
            if (gr < N) v = *(const float4*)&X[(size_t)gr * 128 + kc + kq];
            *(float4*)&xs[r][kq] = v;
        }
        // load W tile: 32 k x 128 cols = 1024 float4, 4 per thread
#pragma unroll
        for (int t = 0; t < 4; ++t) {
            int f = tid + t * 256;
            int kr = f >> 5;            // 0..31
            int cq = (f & 31) * 4;      // 0..124
            *(float4*)&wsh[kr][cq] = *(const float4*)&W[(size_t)(kc + kr) * 128 + cq];
        }
        __syncthreads();
#pragma unroll 8
        for (int k = 0; k < 32; ++k) {
            float xv[8];
#pragma unroll
            for (int j = 0; j < 8; ++j) xv[j] = xs[tr + 16 * j][k];
            float wv[8];
            *(float4*)&wv[0] = *(const float4*)&wsh[k][tc * 8];
            *(float4*)&wv[4] = *(const float4*)&wsh[k][tc * 8 + 4];
#pragma unroll
            for (int j = 0; j < 8; ++j)
#pragma unroll
                for (int l = 0; l < 8; ++l)
                    acc[j][l] = fmaf(xv[j], wv[l], acc[j][l]);
        }
        __syncthreads();
    }
#pragma unroll
    for (int j = 0; j < 8; ++j) {
        int gr = row0 + tr + 16 * j;
        if (gr < N) {
            *(float4*)&H[(size_t)gr * 128 + tc * 8]     = make_float4(acc[j][0], acc[j][1], acc[j][2], acc[j][3]);
            *(float4*)&H[(size_t)gr * 128 + tc * 8 + 4] = make_float4(acc[j][4], acc[j][5], acc[j][6], acc[j][7]);
        }
    }
}

// ---------------- aggregation ----------------

__global__ __launch_bounds__(256) void initagg_kernel(float* __restrict__ agg, const float* __restrict__ bias, int N) {
    int idx = blockIdx.x * 256 + threadIdx.x;
    if (idx < N * 128) agg[idx] = bias[idx & 127];
}

// one edge per 128 threads (2 edges per block); channel-coalesced
__global__ __launch_bounds__(256) void scatter_kernel(const float* __restrict__ h, const int* __restrict__ row,
                                                      const int* __restrict__ col, const float* __restrict__ norm,
                                                      float* __restrict__ agg, int E) {
    int e = blockIdx.x * 2 + (threadIdx.x >> 7);
    int c = threadIdx.x & 127;
    if (e < E) {
        int r = row[e], t = col[e];
        float w = norm[e];
        atomicAdd(&agg[(size_t)t * 128 + c], w * h[(size_t)r * 128 + c]);
    }
}

// ---------------- batchnorm ----------------

__global__ __launch_bounds__(256) void bn_stats(const float* __restrict__ agg, float* __restrict__ sums, int N) {
    __shared__ float s1[256], s2[256];
    int c = threadIdx.x & 127;
    int half = threadIdx.x >> 7;
    float sum = 0.f, sq = 0.f;
    for (int n = blockIdx.x * 2 + half; n < N; n += gridDim.x * 2) {
        float v = agg[(size_t)n * 128 + c];
        sum += v;
        sq += v * v;
    }
    s1[threadIdx.x] = sum;
    s2[threadIdx.x] = sq;
    __syncthreads();
    if (threadIdx.x < 128) {
        sum = s1[threadIdx.x] + s1[threadIdx.x + 128];
        sq  = s2[threadIdx.x] + s2[threadIdx.x + 128];
        atomicAdd(&sums[c], sum);
        atomicAdd(&sums[128 + c], sq);
    }
}

__global__ void bn_finalize(const float* __restrict__ sums, const float* __restrict__ gamma,
                            const float* __restrict__ beta, float* __restrict__ ss, int N) {
    int c = threadIdx.x;  // 128 threads
    float mean = sums[c] / (float)N;
    float var  = sums[128 + c] / (float)N - mean * mean;
    float inv  = rsqrtf(fmaxf(var, 0.0f) + BN_EPS);
    float sc   = gamma[c] * inv;
    ss[c]       = sc;
    ss[128 + c] = beta[c] - mean * sc;
}

__global__ __launch_bounds__(256) void bn_apply(const float* __restrict__ agg, const float* __restrict__ ss,
                                                const float* __restrict__ xprev, float* __restrict__ xout,
                                                int N, int residual) {
    int idx = blockIdx.x * 256 + threadIdx.x;
    if (idx < N * 128) {
        int c = idx & 127;
        float v = fmaf(agg[idx], ss[c], ss[128 + c]);
        v = fmaxf(v, 0.0f);
        if (residual) v = fmaf(0.5f, xprev[idx], v);
        xout[idx] = v;
    }
}

// ---------------- launch ----------------

extern "C" void kernel_launch(void* const* d_in, const int* in_sizes, int n_in,
                              void* d_out, int out_size, void* d_ws, size_t ws_size,
                              hipStream_t stream) {
    const float* emb    = (const float*)d_in[0];
    const float* Ws     = (const float*)d_in[1];
    const float* bs     = (const float*)d_in[2];
    const float* gammas = (const float*)d_in[3];
    const float* betas  = (const float*)d_in[4];
    const int*   ei     = (const int*)d_in[5];

    const int N = in_sizes[0] / 127;
    const int E = in_sizes[5] / 2;
    const int* row = ei;
    const int* col = ei + E;
    float* out = (float*)d_out;

    const size_t NH = (size_t)N * 128;
    float* XA      = (float*)d_ws;
    float* XB      = XA + NH;
    float* deg_src = XB + NH;
    float* dinvb   = deg_src + N;   // holds deg, then dinv in place
    float* normb   = dinvb + N;
    float* sums    = normb + E;     // 256: [sum | sumsq]
    float* ssb     = sums + 256;    // 256: [scale | shift]
    float* agg     = out;           // reuse output buffer as aggregation buffer

    const int NHB = (int)NH;

    // degrees (deg_src and deg contiguous -> one memset)
    hipMemsetAsync(deg_src, 0, sizeof(float) * 2 * (size_t)N, stream);
    deg_kernel<<<(E + 255) / 256, 256, 0, stream>>>(row, col, deg_src, dinvb, E);
    dinv_kernel<<<(N + 255) / 256, 256, 0, stream>>>(dinvb, N);
    initx_kernel<<<(NHB + 255) / 256, 256, 0, stream>>>(emb, deg_src, XA, N);
    norm_kernel<<<(E + 255) / 256, 256, 0, stream>>>(row, col, dinvb, normb, E);

    // layer plumbing: L0: XA -> h(XB) -> XA ; L1: XA -> h(XB) -> XB ; L2: XB -> h(XA) -> out
    const float* xin[3]  = {XA, XA, XB};
    float*       hbuf[3] = {XB, XB, XA};
    float*       xout[3] = {XA, XB, out};

    for (int i = 0; i < 3; ++i) {
        gemm_kernel<<<(N + 127) / 128, 256, 0, stream>>>(xin[i], Ws + (size_t)i * 128 * 128, hbuf[i], N);
        initagg_kernel<<<(NHB + 255) / 256, 256, 0, stream>>>(agg, bs + i * 128, N);
        scatter_kernel<<<(E + 1) / 2, 256, 0, stream>>>(hbuf[i], row, col, normb, agg, E);
        hipMemsetAsync(sums, 0, sizeof(float) * 256, stream);
        bn_stats<<<512, 256, 0, stream>>>(agg, sums, N);
        bn_finalize<<<1, 128, 0, stream>>>(sums, gammas + i * 128, betas + i * 128, ssb, N);
        bn_apply<<<(NHB + 255) / 256, 256, 0, stream>>>(agg, ssb, xin[i], xout[i], N, i > 0 ? 1 : 0);
    }
}

// Round 2
// 1065.823 us; speedup vs baseline: 1.2396x; 1.2396x over previous
//
#include <hip/hip_runtime.h>
#include <math.h>

#define BN_EPS 1e-5f

// ---------------- degree / feature precompute ----------------

__global__ __launch_bounds__(256) void deg_kernel(const int* __restrict__ row, const int* __restrict__ col,
                                                  float* __restrict__ deg_src, float* __restrict__ deg_dst, int E) {
    int e = blockIdx.x * 256 + threadIdx.x;
    if (e < E) {
        atomicAdd(&deg_src[row[e]], 1.0f);
        atomicAdd(&deg_dst[col[e]], 1.0f);
    }
}

// dinv in place; also emit integer in-degree counts for CSR
__global__ __launch_bounds__(256) void dinv_cnt_kernel(float* __restrict__ deg_dst, int* __restrict__ cnt, int N) {
    int n = blockIdx.x * 256 + threadIdx.x;
    if (n < N) {
        float d = deg_dst[n];
        cnt[n] = (int)d;
        deg_dst[n] = (d > 0.0f) ? rsqrtf(d) : 0.0f;
    }
}

__global__ __launch_bounds__(256) void initx_kernel(const float* __restrict__ emb, const float* __restrict__ deg_src,
                                                    float* __restrict__ x, int N) {
    int idx = blockIdx.x * 256 + threadIdx.x;
    if (idx < N * 128) {
        int n = idx >> 7, c = idx & 127;
        x[idx] = (c < 127) ? emb[(size_t)n * 127 + c] : logf(deg_src[n] + 1.0f);
    }
}

// ---------------- CSR build: exclusive scan + fill ----------------

// single block, 1024 threads; each thread serially owns a contiguous chunk
__global__ __launch_bounds__(1024) void scan_kernel(const int* __restrict__ cnt, int* __restrict__ off,
                                                    int* __restrict__ cur, int N) {
    __shared__ int lds[1024];
    const int tid = threadIdx.x;
    const int per = (N + 1023) / 1024;
    const int start = tid * per;
    const int end = min(start + per, N);
    int s = 0;
    for (int i = start; i < end; ++i) s += cnt[i];
    lds[tid] = s;
    __syncthreads();
    for (int d = 1; d < 1024; d <<= 1) {
        int t = (tid >= d) ? lds[tid - d] : 0;
        __syncthreads();
        lds[tid] += t;
        __syncthreads();
    }
    int prefix = lds[tid] - s;  // exclusive
    for (int i = start; i < end; ++i) {
        off[i] = prefix;
        cur[i] = prefix;
        prefix += cnt[i];
    }
    if (tid == 1023) off[N] = lds[1023];
}

__global__ __launch_bounds__(256) void fill_kernel(const int* __restrict__ row, const int* __restrict__ col,
                                                   const float* __restrict__ dinv, int* __restrict__ cur,
                                                   int* __restrict__ srcs, float* __restrict__ wts, int E) {
    int e = blockIdx.x * 256 + threadIdx.x;
    if (e < E) {
        int r = row[e], t = col[e];
        int p = atomicAdd(&cur[t], 1);
        srcs[p] = r;
        wts[p] = dinv[r] * dinv[t];
    }
}

// ---------------- GEMM: H[N,128] = X[N,128] @ W[128,128] (f32, vector ALU) ----------------

__global__ __launch_bounds__(256) void gemm_kernel(const float* __restrict__ X, const float* __restrict__ W,
                                                   float* __restrict__ H, int N) {
    __shared__ float xs[128][36];
    __shared__ float wsh[32][132];
    const int tid = threadIdx.x;
    const int tr = tid & 15;
    const int tc = tid >> 4;
    const int row0 = blockIdx.x * 128;

    float acc[8][8];
#pragma unroll
    for (int a = 0; a < 8; ++a)
#pragma unroll
        for (int b = 0; b < 8; ++b) acc[a][b] = 0.0f;

    for (int kc = 0; kc < 128; kc += 32) {
#pragma unroll
        for (int t = 0; t < 4; ++t) {
            int f = tid + t * 256;
            int r = f >> 3;
            int kq = (f & 7) * 4;
            int gr = row0 + r;
            float4 v = make_float4(0.f, 0.f, 0.f, 0.f);
            if (gr < N) v = *(const float4*)&X[(size_t)gr * 128 + kc + kq];
            *(float4*)&xs[r][kq] = v;
        }
#pragma unroll
        for (int t = 0; t < 4; ++t) {
            int f = tid + t * 256;
            int kr = f >> 5;
            int cq = (f & 31) * 4;
            *(float4*)&wsh[kr][cq] = *(const float4*)&W[(size_t)(kc + kr) * 128 + cq];
        }
        __syncthreads();
#pragma unroll 8
        for (int k = 0; k < 32; ++k) {
            float xv[8];
#pragma unroll
            for (int j = 0; j < 8; ++j) xv[j] = xs[tr + 16 * j][k];
            float wv[8];
            *(float4*)&wv[0] = *(const float4*)&wsh[k][tc * 8];
            *(float4*)&wv[4] = *(const float4*)&wsh[k][tc * 8 + 4];
#pragma unroll
            for (int j = 0; j < 8; ++j)
#pragma unroll
                for (int l = 0; l < 8; ++l)
                    acc[j][l] = fmaf(xv[j], wv[l], acc[j][l]);
        }
        __syncthreads();
    }
#pragma unroll
    for (int j = 0; j < 8; ++j) {
        int gr = row0 + tr + 16 * j;
        if (gr < N) {
            *(float4*)&H[(size_t)gr * 128 + tc * 8]     = make_float4(acc[j][0], acc[j][1], acc[j][2], acc[j][3]);
            *(float4*)&H[(size_t)gr * 128 + tc * 8 + 4] = make_float4(acc[j][4], acc[j][5], acc[j][6], acc[j][7]);
        }
    }
}

// ---------------- CSR gather + bias + fused BN partial stats ----------------
// 256 threads = 2 nodes x 128 channels; each wave is node-uniform.

__global__ __launch_bounds__(256) void gather_kernel(const float* __restrict__ h, const int* __restrict__ off,
                                                     const int* __restrict__ srcs, const float* __restrict__ wts,
                                                     const float* __restrict__ bias, float* __restrict__ agg,
                                                     float* __restrict__ sums, int N) {
    __shared__ float s1[256], s2[256];
    const int tid = threadIdx.x;
    const int c = tid & 127;
    const int half = tid >> 7;
    const float b = bias[c];
    float psum = 0.f, psq = 0.f;

    for (int base = blockIdx.x * 2; base < N; base += gridDim.x * 2) {
        int n = __builtin_amdgcn_readfirstlane(base + half);   // wave-uniform
        int s = off[n], e = off[n + 1];
        float acc = b;
        for (int i = s; i < e; ++i)
            acc = fmaf(wts[i], h[(size_t)srcs[i] * 128 + c], acc);
        agg[(size_t)n * 128 + c] = acc;
        psum += acc;
        psq = fmaf(acc, acc, psq);
    }
    s1[tid] = psum;
    s2[tid] = psq;
    __syncthreads();
    if (tid < 128) {
        atomicAdd(&sums[c], s1[tid] + s1[tid + 128]);
        atomicAdd(&sums[128 + c], s2[tid] + s2[tid + 128]);
    }
}

// ---------------- batchnorm finalize / apply ----------------

__global__ void bn_finalize(const float* __restrict__ sums, const float* __restrict__ gamma,
                            const float* __restrict__ beta, float* __restrict__ ss, int N) {
    int c = threadIdx.x;  // 128 threads
    float mean = sums[c] / (float)N;
    float var  = sums[128 + c] / (float)N - mean * mean;
    float inv  = rsqrtf(fmaxf(var, 0.0f) + BN_EPS);
    float sc   = gamma[c] * inv;
    ss[c]       = sc;
    ss[128 + c] = beta[c] - mean * sc;
}

__global__ __launch_bounds__(256) void bn_apply(const float* __restrict__ agg, const float* __restrict__ ss,
                                                const float* __restrict__ xprev, float* __restrict__ xout,
                                                int N, int residual) {
    int idx = blockIdx.x * 256 + threadIdx.x;
    if (idx < N * 128) {
        int c = idx & 127;
        float v = fmaf(agg[idx], ss[c], ss[128 + c]);
        v = fmaxf(v, 0.0f);
        if (residual) v = fmaf(0.5f, xprev[idx], v);
        xout[idx] = v;
    }
}

// ---------------- launch ----------------

extern "C" void kernel_launch(void* const* d_in, const int* in_sizes, int n_in,
                              void* d_out, int out_size, void* d_ws, size_t ws_size,
                              hipStream_t stream) {
    const float* emb    = (const float*)d_in[0];
    const float* Ws     = (const float*)d_in[1];
    const float* bs     = (const float*)d_in[2];
    const float* gammas = (const float*)d_in[3];
    const float* betas  = (const float*)d_in[4];
    const int*   ei     = (const int*)d_in[5];

    const int N = in_sizes[0] / 127;
    const int E = in_sizes[5] / 2;
    const int* row = ei;
    const int* col = ei + E;
    float* out = (float*)d_out;

    const size_t NH = (size_t)N * 128;
    float* XA      = (float*)d_ws;
    float* XB      = XA + NH;
    float* deg_src = XB + NH;       // N floats (out-degree counts)
    float* dinvb   = deg_src + N;   // N floats: deg, then dinv in place
    float* wts     = dinvb + N;     // E floats (CSR edge weights)
    int*   cnt     = (int*)(wts + E);   // N
    int*   off     = cnt + N;           // N+1
    int*   cur     = off + N + 1;       // N
    int*   srcs    = cur + N;           // E
    float* sums    = (float*)(srcs + E);  // 256: [sum | sumsq]
    float* ssb     = sums + 256;          // 256: [scale | shift]
    float* agg     = out;

    const int NHB = (int)NH;

    // degrees (deg_src and deg_dst contiguous -> one memset)
    hipMemsetAsync(deg_src, 0, sizeof(float) * 2 * (size_t)N, stream);
    deg_kernel<<<(E + 255) / 256, 256, 0, stream>>>(row, col, deg_src, dinvb, E);
    dinv_cnt_kernel<<<(N + 255) / 256, 256, 0, stream>>>(dinvb, cnt, N);
    initx_kernel<<<(NHB + 255) / 256, 256, 0, stream>>>(emb, deg_src, XA, N);
    scan_kernel<<<1, 1024, 0, stream>>>(cnt, off, cur, N);
    fill_kernel<<<(E + 255) / 256, 256, 0, stream>>>(row, col, dinvb, cur, srcs, wts, E);

    // layer plumbing: L0: XA -> h(XB) -> XA ; L1: XA -> h(XB) -> XB ; L2: XB -> h(XA) -> out
    const float* xin[3]  = {XA, XA, XB};
    float*       hbuf[3] = {XB, XB, XA};
    float*       xout[3] = {XA, XB, out};

    for (int i = 0; i < 3; ++i) {
        gemm_kernel<<<(N + 127) / 128, 256, 0, stream>>>(xin[i], Ws + (size_t)i * 128 * 128, hbuf[i], N);
        hipMemsetAsync(sums, 0, sizeof(float) * 256, stream);
        gather_kernel<<<1024, 256, 0, stream>>>(hbuf[i], off, srcs, wts, bs + i * 128, agg, sums, N);
        bn_finalize<<<1, 128, 0, stream>>>(sums, gammas + i * 128, betas + i * 128, ssb, N);
        bn_apply<<<(NHB + 255) / 256, 256, 0, stream>>>(agg, ssb, xin[i], xout[i], N, i > 0 ? 1 : 0);
    }
}

// Round 3
// 747.820 us; speedup vs baseline: 1.7667x; 1.4252x over previous
//
#include <hip/hip_runtime.h>
#include <math.h>

#define BN_EPS 1e-5f

// ---------------- degree / feature precompute ----------------

__global__ __launch_bounds__(256) void deg_kernel(const int* __restrict__ row, const int* __restrict__ col,
                                                  float* __restrict__ deg_src, float* __restrict__ deg_dst, int E) {
    int e = blockIdx.x * 256 + threadIdx.x;
    if (e < E) {
        atomicAdd(&deg_src[row[e]], 1.0f);
        atomicAdd(&deg_dst[col[e]], 1.0f);
    }
}

// dinv in place; also emit integer in-degree counts for CSR
__global__ __launch_bounds__(256) void dinv_cnt_kernel(float* __restrict__ deg_dst, int* __restrict__ cnt, int N) {
    int n = blockIdx.x * 256 + threadIdx.x;
    if (n < N) {
        float d = deg_dst[n];
        cnt[n] = (int)d;
        deg_dst[n] = (d > 0.0f) ? rsqrtf(d) : 0.0f;
    }
}

__global__ __launch_bounds__(256) void initx_kernel(const float* __restrict__ emb, const float* __restrict__ deg_src,
                                                    float* __restrict__ x, int N) {
    int idx = blockIdx.x * 256 + threadIdx.x;
    if (idx < N * 128) {
        int n = idx >> 7, c = idx & 127;
        x[idx] = (c < 127) ? emb[(size_t)n * 127 + c] : logf(deg_src[n] + 1.0f);
    }
}

// ---------------- CSR build: hierarchical exclusive scan + fill ----------------
// 256 blocks x 256 threads, PT elements per thread (contiguous).

__global__ __launch_bounds__(256) void scan_pass1(const int* __restrict__ cnt, int* __restrict__ blockSums,
                                                  int N, int PT) {
    __shared__ int lds[256];
    const int tid = threadIdx.x;
    const int start = (blockIdx.x * 256 + tid) * PT;
    int s = 0;
    for (int i = 0; i < PT; ++i) {
        int idx = start + i;
        if (idx < N) s += cnt[idx];
    }
    lds[tid] = s;
    __syncthreads();
    for (int d = 128; d > 0; d >>= 1) {
        if (tid < d) lds[tid] += lds[tid + d];
        __syncthreads();
    }
    if (tid == 0) blockSums[blockIdx.x] = lds[0];
}

__global__ __launch_bounds__(256) void scan_pass2(const int* __restrict__ blockSums, int* __restrict__ blockOffs) {
    __shared__ int lds[256];
    const int tid = threadIdx.x;
    int v = blockSums[tid];
    lds[tid] = v;
    __syncthreads();
    for (int d = 1; d < 256; d <<= 1) {
        int t = (tid >= d) ? lds[tid - d] : 0;
        __syncthreads();
        lds[tid] += t;
        __syncthreads();
    }
    blockOffs[tid] = lds[tid] - v;  // exclusive
}

__global__ __launch_bounds__(256) void scan_pass3(const int* __restrict__ cnt, const int* __restrict__ blockOffs,
                                                  int* __restrict__ off, int* __restrict__ cur,
                                                  int N, int PT, int E) {
    __shared__ int lds[256];
    const int tid = threadIdx.x;
    const int start = (blockIdx.x * 256 + tid) * PT;
    int s = 0;
    for (int i = 0; i < PT; ++i) {
        int idx = start + i;
        if (idx < N) s += cnt[idx];
    }
    lds[tid] = s;
    __syncthreads();
    for (int d = 1; d < 256; d <<= 1) {
        int t = (tid >= d) ? lds[tid - d] : 0;
        __syncthreads();
        lds[tid] += t;
        __syncthreads();
    }
    int prefix = blockOffs[blockIdx.x] + lds[tid] - s;
    for (int i = 0; i < PT; ++i) {
        int idx = start + i;
        if (idx < N) {
            off[idx] = prefix;
            cur[idx] = prefix;
            prefix += cnt[idx];
        }
    }
    if (blockIdx.x == 0 && tid == 0) off[N] = E;
}

__global__ __launch_bounds__(256) void fill_kernel(const int* __restrict__ row, const int* __restrict__ col,
                                                   const float* __restrict__ dinv, int* __restrict__ cur,
                                                   int* __restrict__ srcs, float* __restrict__ wts, int E) {
    int e = blockIdx.x * 256 + threadIdx.x;
    if (e < E) {
        int r = row[e], t = col[e];
        int p = atomicAdd(&cur[t], 1);
        srcs[p] = r;
        wts[p] = dinv[r] * dinv[t];
    }
}

// ---------------- GEMM: H[N,128] = X[N,128] @ W[128,128] (f32, vector ALU) ----------------

__global__ __launch_bounds__(256) void gemm_kernel(const float* __restrict__ X, const float* __restrict__ W,
                                                   float* __restrict__ H, int N) {
    __shared__ float xs[128][36];
    __shared__ float wsh[32][132];
    const int tid = threadIdx.x;
    const int tr = tid & 15;
    const int tc = tid >> 4;
    const int row0 = blockIdx.x * 128;

    float acc[8][8];
#pragma unroll
    for (int a = 0; a < 8; ++a)
#pragma unroll
        for (int b = 0; b < 8; ++b) acc[a][b] = 0.0f;

    for (int kc = 0; kc < 128; kc += 32) {
#pragma unroll
        for (int t = 0; t < 4; ++t) {
            int f = tid + t * 256;
            int r = f >> 3;
            int kq = (f & 7) * 4;
            int gr = row0 + r;
            float4 v = make_float4(0.f, 0.f, 0.f, 0.f);
            if (gr < N) v = *(const float4*)&X[(size_t)gr * 128 + kc + kq];
            *(float4*)&xs[r][kq] = v;
        }
#pragma unroll
        for (int t = 0; t < 4; ++t) {
            int f = tid + t * 256;
            int kr = f >> 5;
            int cq = (f & 31) * 4;
            *(float4*)&wsh[kr][cq] = *(const float4*)&W[(size_t)(kc + kr) * 128 + cq];
        }
        __syncthreads();
#pragma unroll 8
        for (int k = 0; k < 32; ++k) {
            float xv[8];
#pragma unroll
            for (int j = 0; j < 8; ++j) xv[j] = xs[tr + 16 * j][k];
            float wv[8];
            *(float4*)&wv[0] = *(const float4*)&wsh[k][tc * 8];
            *(float4*)&wv[4] = *(const float4*)&wsh[k][tc * 8 + 4];
#pragma unroll
            for (int j = 0; j < 8; ++j)
#pragma unroll
                for (int l = 0; l < 8; ++l)
                    acc[j][l] = fmaf(xv[j], wv[l], acc[j][l]);
        }
        __syncthreads();
    }
#pragma unroll
    for (int j = 0; j < 8; ++j) {
        int gr = row0 + tr + 16 * j;
        if (gr < N) {
            *(float4*)&H[(size_t)gr * 128 + tc * 8]     = make_float4(acc[j][0], acc[j][1], acc[j][2], acc[j][3]);
            *(float4*)&H[(size_t)gr * 128 + tc * 8 + 4] = make_float4(acc[j][4], acc[j][5], acc[j][6], acc[j][7]);
        }
    }
}

// ---------------- CSR gather + bias + fused BN partial stats ----------------
// 256 threads = 2 nodes x 128 channels; each wave is node-uniform.
// Inner loop unrolled x4: 4 independent meta loads + 4 independent h-row loads (MLP).

__global__ __launch_bounds__(256) void gather_kernel(const float* __restrict__ h, const int* __restrict__ off,
                                                     const int* __restrict__ srcs, const float* __restrict__ wts,
                                                     const float* __restrict__ bias, float* __restrict__ agg,
                                                     float* __restrict__ sums, int N) {
    __shared__ float s1[256], s2[256];
    const int tid = threadIdx.x;
    const int c = tid & 127;
    const int half = tid >> 7;
    const float b = bias[c];
    float psum = 0.f, psq = 0.f;

    for (int base = blockIdx.x * 2; base < N; base += gridDim.x * 2) {
        int n = __builtin_amdgcn_readfirstlane(base + half);   // wave-uniform
        int s = off[n], e = off[n + 1];
        float acc = b;
        int i = s;
        for (; i + 4 <= e; i += 4) {
            int   r0 = srcs[i],     r1 = srcs[i + 1], r2 = srcs[i + 2], r3 = srcs[i + 3];
            float w0 = wts[i],      w1 = wts[i + 1],  w2 = wts[i + 2],  w3 = wts[i + 3];
            float h0 = h[(size_t)r0 * 128 + c];
            float h1 = h[(size_t)r1 * 128 + c];
            float h2 = h[(size_t)r2 * 128 + c];
            float h3 = h[(size_t)r3 * 128 + c];
            acc = fmaf(w0, h0, acc);
            acc = fmaf(w1, h1, acc);
            acc = fmaf(w2, h2, acc);
            acc = fmaf(w3, h3, acc);
        }
        for (; i < e; ++i)
            acc = fmaf(wts[i], h[(size_t)srcs[i] * 128 + c], acc);
        agg[(size_t)n * 128 + c] = acc;
        psum += acc;
        psq = fmaf(acc, acc, psq);
    }
    s1[tid] = psum;
    s2[tid] = psq;
    __syncthreads();
    if (tid < 128) {
        atomicAdd(&sums[c], s1[tid] + s1[tid + 128]);
        atomicAdd(&sums[128 + c], s2[tid] + s2[tid + 128]);
    }
}

// ---------------- batchnorm finalize / apply ----------------

__global__ void bn_finalize(const float* __restrict__ sums, const float* __restrict__ gamma,
                            const float* __restrict__ beta, float* __restrict__ ss, int N) {
    int c = threadIdx.x;  // 128 threads
    float mean = sums[c] / (float)N;
    float var  = sums[128 + c] / (float)N - mean * mean;
    float inv  = rsqrtf(fmaxf(var, 0.0f) + BN_EPS);
    float sc   = gamma[c] * inv;
    ss[c]       = sc;
    ss[128 + c] = beta[c] - mean * sc;
}

__global__ __launch_bounds__(256) void bn_apply(const float* __restrict__ agg, const float* __restrict__ ss,
                                                const float* __restrict__ xprev, float* __restrict__ xout,
                                                int N, int residual) {
    int idx = blockIdx.x * 256 + threadIdx.x;
    if (idx < N * 128) {
        int c = idx & 127;
        float v = fmaf(agg[idx], ss[c], ss[128 + c]);
        v = fmaxf(v, 0.0f);
        if (residual) v = fmaf(0.5f, xprev[idx], v);
        xout[idx] = v;
    }
}

// ---------------- launch ----------------

extern "C" void kernel_launch(void* const* d_in, const int* in_sizes, int n_in,
                              void* d_out, int out_size, void* d_ws, size_t ws_size,
                              hipStream_t stream) {
    const float* emb    = (const float*)d_in[0];
    const float* Ws     = (const float*)d_in[1];
    const float* bs     = (const float*)d_in[2];
    const float* gammas = (const float*)d_in[3];
    const float* betas  = (const float*)d_in[4];
    const int*   ei     = (const int*)d_in[5];

    const int N = in_sizes[0] / 127;
    const int E = in_sizes[5] / 2;
    const int* row = ei;
    const int* col = ei + E;
    float* out = (float*)d_out;

    const size_t NH = (size_t)N * 128;
    float* XA      = (float*)d_ws;
    float* XB      = XA + NH;
    float* deg_src = XB + NH;       // N floats (out-degree counts)
    float* dinvb   = deg_src + N;   // N floats: deg, then dinv in place
    float* wts     = dinvb + N;     // E floats (CSR edge weights)
    int*   cnt     = (int*)(wts + E);   // N
    int*   off     = cnt + N;           // N+1
    int*   cur     = off + N + 1;       // N
    int*   srcs    = cur + N;           // E
    float* sums    = (float*)(srcs + E);  // 256: [sum | sumsq]
    float* ssb     = sums + 256;          // 256: [scale | shift]
    int*   blockSums = (int*)(ssb + 256); // 256
    int*   blockOffs = blockSums + 256;   // 256
    float* agg     = out;

    const int NHB = (int)NH;
    const int PT = (N + 65535) / 65536;   // elems per scan thread

    // degrees (deg_src and deg_dst contiguous -> one memset)
    hipMemsetAsync(deg_src, 0, sizeof(float) * 2 * (size_t)N, stream);
    deg_kernel<<<(E + 255) / 256, 256, 0, stream>>>(row, col, deg_src, dinvb, E);
    dinv_cnt_kernel<<<(N + 255) / 256, 256, 0, stream>>>(dinvb, cnt, N);
    initx_kernel<<<(NHB + 255) / 256, 256, 0, stream>>>(emb, deg_src, XA, N);
    scan_pass1<<<256, 256, 0, stream>>>(cnt, blockSums, N, PT);
    scan_pass2<<<1, 256, 0, stream>>>(blockSums, blockOffs);
    scan_pass3<<<256, 256, 0, stream>>>(cnt, blockOffs, off, cur, N, PT, E);
    fill_kernel<<<(E + 255) / 256, 256, 0, stream>>>(row, col, dinvb, cur, srcs, wts, E);

    // layer plumbing: L0: XA -> h(XB) -> XA ; L1: XA -> h(XB) -> XB ; L2: XB -> h(XA) -> out
    const float* xin[3]  = {XA, XA, XB};
    float*       hbuf[3] = {XB, XB, XA};
    float*       xout[3] = {XA, XB, out};

    for (int i = 0; i < 3; ++i) {
        gemm_kernel<<<(N + 127) / 128, 256, 0, stream>>>(xin[i], Ws + (size_t)i * 128 * 128, hbuf[i], N);
        hipMemsetAsync(sums, 0, sizeof(float) * 256, stream);
        gather_kernel<<<2048, 256, 0, stream>>>(hbuf[i], off, srcs, wts, bs + i * 128, agg, sums, N);
        bn_finalize<<<1, 128, 0, stream>>>(sums, gammas + i * 128, betas + i * 128, ssb, N);
        bn_apply<<<(NHB + 255) / 256, 256, 0, stream>>>(agg, ssb, xin[i], xout[i], N, i > 0 ? 1 : 0);
    }
}

// Round 4
// 646.994 us; speedup vs baseline: 2.0421x; 1.1558x over previous
//
#include <hip/hip_runtime.h>
#include <hip/hip_bf16.h>
#include <math.h>

#define BN_EPS 1e-5f

typedef __attribute__((ext_vector_type(8))) short short8v;   // 8 x bf16
typedef __attribute__((ext_vector_type(4))) float f32x4;

__device__ inline float bf_lo(unsigned int p) { return __uint_as_float(p << 16); }
__device__ inline float bf_hi(unsigned int p) { return __uint_as_float(p & 0xffff0000u); }
__device__ inline unsigned int packbf(float a, float b) {
    unsigned short lo = __builtin_bit_cast(unsigned short, __float2bfloat16(a));
    unsigned short hi = __builtin_bit_cast(unsigned short, __float2bfloat16(b));
    return (unsigned int)lo | ((unsigned int)hi << 16);
}

// ---------------- degree / feature precompute ----------------

__global__ __launch_bounds__(256) void deg_kernel(const int* __restrict__ row, const int* __restrict__ col,
                                                  float* __restrict__ deg_src, float* __restrict__ deg_dst, int E) {
    int e = blockIdx.x * 256 + threadIdx.x;
    if (e < E) {
        atomicAdd(&deg_src[row[e]], 1.0f);
        atomicAdd(&deg_dst[col[e]], 1.0f);
    }
}

__global__ __launch_bounds__(256) void dinv_cnt_kernel(float* __restrict__ deg_dst, int* __restrict__ cnt, int N) {
    int n = blockIdx.x * 256 + threadIdx.x;
    if (n < N) {
        float d = deg_dst[n];
        cnt[n] = (int)d;
        deg_dst[n] = (d > 0.0f) ? rsqrtf(d) : 0.0f;
    }
}

// x in bf16: thread handles channel pair (2p, 2p+1) of node n
__global__ __launch_bounds__(256) void initx_kernel(const float* __restrict__ emb, const float* __restrict__ deg_src,
                                                    unsigned int* __restrict__ x, int N) {
    int idx = blockIdx.x * 256 + threadIdx.x;   // N*64 pairs
    if (idx < N * 64) {
        int n = idx >> 6, p = idx & 63;
        float v0, v1;
        if (p < 63) {
            v0 = emb[(size_t)n * 127 + 2 * p];
            v1 = emb[(size_t)n * 127 + 2 * p + 1];
        } else {
            v0 = emb[(size_t)n * 127 + 126];
            v1 = logf(deg_src[n] + 1.0f);
        }
        x[idx] = packbf(v0, v1);
    }
}

// W^T in bf16: Wt[l][c][k] = W[l][k][c]
__global__ __launch_bounds__(256) void wt_kernel(const float* __restrict__ Ws, __hip_bfloat16* __restrict__ Wt) {
    int idx = blockIdx.x * 256 + threadIdx.x;
    if (idx < 3 * 16384) {
        int l = idx >> 14, rem = idx & 16383, c = rem >> 7, k = rem & 127;
        Wt[idx] = __float2bfloat16(Ws[(l << 14) + (k << 7) + c]);
    }
}

// ---------------- CSR build: hierarchical exclusive scan + fill ----------------

__global__ __launch_bounds__(256) void scan_pass1(const int* __restrict__ cnt, int* __restrict__ blockSums,
                                                  int N, int PT) {
    __shared__ int lds[256];
    const int tid = threadIdx.x;
    const int start = (blockIdx.x * 256 + tid) * PT;
    int s = 0;
    for (int i = 0; i < PT; ++i) {
        int idx = start + i;
        if (idx < N) s += cnt[idx];
    }
    lds[tid] = s;
    __syncthreads();
    for (int d = 128; d > 0; d >>= 1) {
        if (tid < d) lds[tid] += lds[tid + d];
        __syncthreads();
    }
    if (tid == 0) blockSums[blockIdx.x] = lds[0];
}

__global__ __launch_bounds__(256) void scan_pass2(const int* __restrict__ blockSums, int* __restrict__ blockOffs) {
    __shared__ int lds[256];
    const int tid = threadIdx.x;
    int v = blockSums[tid];
    lds[tid] = v;
    __syncthreads();
    for (int d = 1; d < 256; d <<= 1) {
        int t = (tid >= d) ? lds[tid - d] : 0;
        __syncthreads();
        lds[tid] += t;
        __syncthreads();
    }
    blockOffs[tid] = lds[tid] - v;
}

__global__ __launch_bounds__(256) void scan_pass3(const int* __restrict__ cnt, const int* __restrict__ blockOffs,
                                                  int* __restrict__ off, int* __restrict__ cur,
                                                  int N, int PT, int E) {
    __shared__ int lds[256];
    const int tid = threadIdx.x;
    const int start = (blockIdx.x * 256 + tid) * PT;
    int s = 0;
    for (int i = 0; i < PT; ++i) {
        int idx = start + i;
        if (idx < N) s += cnt[idx];
    }
    lds[tid] = s;
    __syncthreads();
    for (int d = 1; d < 256; d <<= 1) {
        int t = (tid >= d) ? lds[tid - d] : 0;
        __syncthreads();
        lds[tid] += t;
        __syncthreads();
    }
    int prefix = blockOffs[blockIdx.x] + lds[tid] - s;
    for (int i = 0; i < PT; ++i) {
        int idx = start + i;
        if (idx < N) {
            off[idx] = prefix;
            cur[idx] = prefix;
            prefix += cnt[idx];
        }
    }
    if (blockIdx.x == 0 && tid == 0) off[N] = E;
}

__global__ __launch_bounds__(256) void fill_kernel(const int* __restrict__ row, const int* __restrict__ col,
                                                   const float* __restrict__ dinv, int* __restrict__ cur,
                                                   int* __restrict__ srcs, float* __restrict__ wts, int E) {
    int e = blockIdx.x * 256 + threadIdx.x;
    if (e < E) {
        int r = row[e], t = col[e];
        int p = atomicAdd(&cur[t], 1);
        srcs[p] = r;
        wts[p] = dinv[r] * dinv[t];
    }
}

// ---------------- GEMM: H[N,128] = X[N,128] @ W[128,128], bf16 MFMA 16x16x32 ----------------
// Wave-job = (stripe of 16 rows, col-half of 64). B-frags (4 col-tiles x 4 k-steps) in registers.
// A-frag layout: lane holds row=lane&15, k=(lane>>4)*8+j (8 contiguous bf16).
// C/D layout: col=lane&15, row=(lane>>4)*4+reg  [m89-verified].

__global__ __launch_bounds__(256) void gemm_mfma(const __hip_bfloat16* __restrict__ X,
                                                 const __hip_bfloat16* __restrict__ Wt,
                                                 __hip_bfloat16* __restrict__ H, int nStripes, int N) {
    const int lane = threadIdx.x & 63;
    const int wv = threadIdx.x >> 6;
    const int r = lane & 15;
    const int q = lane >> 4;
    const int ch = (blockIdx.x * 4 + wv) & 1;   // stride gridDim*4 is even -> constant per wave

    short8v bfrag[4][4];
#pragma unroll
    for (int ct = 0; ct < 4; ++ct)
#pragma unroll
        for (int kk = 0; kk < 4; ++kk)
            bfrag[ct][kk] = *(const short8v*)(Wt + ((ch * 64 + ct * 16 + r) << 7) + kk * 32 + q * 8);

    const int totalJobs = nStripes * 2;
    for (int job = blockIdx.x * 4 + wv; job < totalJobs; job += gridDim.x * 4) {
        const int s = job >> 1;
        const int arow = s * 16 + r;
        short8v a0 = {}, a1 = {}, a2 = {}, a3 = {};
        if (arow < N) {
            const __hip_bfloat16* xp = X + ((size_t)arow << 7) + q * 8;
            a0 = *(const short8v*)(xp);
            a1 = *(const short8v*)(xp + 32);
            a2 = *(const short8v*)(xp + 64);
            a3 = *(const short8v*)(xp + 96);
        }
        f32x4 acc[4];
#pragma unroll
        for (int ct = 0; ct < 4; ++ct) {
            f32x4 c = {0.f, 0.f, 0.f, 0.f};
            c = __builtin_amdgcn_mfma_f32_16x16x32_bf16(a0, bfrag[ct][0], c, 0, 0, 0);
            c = __builtin_amdgcn_mfma_f32_16x16x32_bf16(a1, bfrag[ct][1], c, 0, 0, 0);
            c = __builtin_amdgcn_mfma_f32_16x16x32_bf16(a2, bfrag[ct][2], c, 0, 0, 0);
            c = __builtin_amdgcn_mfma_f32_16x16x32_bf16(a3, bfrag[ct][3], c, 0, 0, 0);
            acc[ct] = c;
        }
#pragma unroll
        for (int g = 0; g < 4; ++g) {
            int grow = s * 16 + q * 4 + g;
            if (grow < N) {
                __hip_bfloat16* hp = H + ((size_t)grow << 7) + ch * 64 + r;
#pragma unroll
                for (int ct = 0; ct < 4; ++ct)
                    hp[ct * 16] = __float2bfloat16(acc[ct][g]);
            }
        }
    }
}

// ---------------- CSR gather (bf16 h) + bias + fused BN partial stats ----------------
// 256 threads = 4 waves = 4 nodes; lane handles channel pair (2*lane, 2*lane+1).

__global__ __launch_bounds__(256) void gather_kernel(const __hip_bfloat16* __restrict__ h,
                                                     const int* __restrict__ off, const int* __restrict__ srcs,
                                                     const float* __restrict__ wts, const float* __restrict__ bias,
                                                     float* __restrict__ agg, float* __restrict__ sums, int N) {
    __shared__ float l0[256], l1[256], l2[256], l3[256];
    const int tid = threadIdx.x;
    const int lane = tid & 63;
    const int w = tid >> 6;
    const int c0 = lane * 2;
    const float b0 = bias[c0], b1 = bias[c0 + 1];
    float ps0 = 0.f, ps1 = 0.f, pq0 = 0.f, pq1 = 0.f;

    for (int base = blockIdx.x * 4; base < N; base += gridDim.x * 4) {
        int n = __builtin_amdgcn_readfirstlane(base + w);
        if (n < N) {
            int s = off[n], e = off[n + 1];
            float a0 = b0, a1 = b1;
            int i = s;
            for (; i + 4 <= e; i += 4) {
                int   r0 = srcs[i],     r1 = srcs[i + 1], r2 = srcs[i + 2], r3 = srcs[i + 3];
                float w0 = wts[i],      w1 = wts[i + 1],  w2 = wts[i + 2],  w3 = wts[i + 3];
                unsigned int p0 = *(const unsigned int*)(h + ((size_t)r0 << 7) + c0);
                unsigned int p1 = *(const unsigned int*)(h + ((size_t)r1 << 7) + c0);
                unsigned int p2 = *(const unsigned int*)(h + ((size_t)r2 << 7) + c0);
                unsigned int p3 = *(const unsigned int*)(h + ((size_t)r3 << 7) + c0);
                a0 = fmaf(w0, bf_lo(p0), a0); a1 = fmaf(w0, bf_hi(p0), a1);
                a0 = fmaf(w1, bf_lo(p1), a0); a1 = fmaf(w1, bf_hi(p1), a1);
                a0 = fmaf(w2, bf_lo(p2), a0); a1 = fmaf(w2, bf_hi(p2), a1);
                a0 = fmaf(w3, bf_lo(p3), a0); a1 = fmaf(w3, bf_hi(p3), a1);
            }
            for (; i < e; ++i) {
                float wt = wts[i];
                unsigned int p = *(const unsigned int*)(h + ((size_t)srcs[i] << 7) + c0);
                a0 = fmaf(wt, bf_lo(p), a0); a1 = fmaf(wt, bf_hi(p), a1);
            }
            *(float2*)&agg[((size_t)n << 7) + c0] = make_float2(a0, a1);
            ps0 += a0; ps1 += a1;
            pq0 = fmaf(a0, a0, pq0); pq1 = fmaf(a1, a1, pq1);
        }
    }
    l0[tid] = ps0; l1[tid] = ps1; l2[tid] = pq0; l3[tid] = pq1;
    __syncthreads();
    if (tid < 64) {
        atomicAdd(&sums[2 * tid], l0[tid] + l0[tid + 64] + l0[tid + 128] + l0[tid + 192]);
    } else if (tid < 128) {
        int L = tid - 64;
        atomicAdd(&sums[2 * L + 1], l1[L] + l1[L + 64] + l1[L + 128] + l1[L + 192]);
    } else if (tid < 192) {
        int L = tid - 128;
        atomicAdd(&sums[128 + 2 * L], l2[L] + l2[L + 64] + l2[L + 128] + l2[L + 192]);
    } else {
        int L = tid - 192;
        atomicAdd(&sums[128 + 2 * L + 1], l3[L] + l3[L + 64] + l3[L + 128] + l3[L + 192]);
    }
}

// ---------------- batchnorm finalize / apply ----------------

__global__ void bn_finalize(const float* __restrict__ sums, const float* __restrict__ gamma,
                            const float* __restrict__ beta, float* __restrict__ ss, int N) {
    int c = threadIdx.x;  // 128 threads
    float mean = sums[c] / (float)N;
    float var  = sums[128 + c] / (float)N - mean * mean;
    float inv  = rsqrtf(fmaxf(var, 0.0f) + BN_EPS);
    float sc   = gamma[c] * inv;
    ss[c]       = sc;
    ss[128 + c] = beta[c] - mean * sc;
}

// MODE 0: bf16 out, no residual; MODE 1: bf16 out + residual; MODE 2: f32 out + residual
template <int MODE>
__global__ __launch_bounds__(256) void bn_apply(const float* __restrict__ agg, const float* __restrict__ ss,
                                                const unsigned int* __restrict__ xprev, void* __restrict__ xout,
                                                int NH2) {
    int idx = blockIdx.x * 256 + threadIdx.x;   // pair index
    if (idx < NH2) {
        int c0 = (idx * 2) & 127;
        float2 v = *(const float2*)&agg[(size_t)idx * 2];
        float r0 = fmaxf(fmaf(v.x, ss[c0],     ss[128 + c0]),     0.0f);
        float r1 = fmaxf(fmaf(v.y, ss[c0 + 1], ss[128 + c0 + 1]), 0.0f);
        if (MODE >= 1) {
            unsigned int xp = xprev[idx];
            r0 = fmaf(0.5f, bf_lo(xp), r0);
            r1 = fmaf(0.5f, bf_hi(xp), r1);
        }
        if (MODE == 2) {
            *(float2*)((float*)xout + (size_t)idx * 2) = make_float2(r0, r1);
        } else {
            ((unsigned int*)xout)[idx] = packbf(r0, r1);
        }
    }
}

// ---------------- launch ----------------

extern "C" void kernel_launch(void* const* d_in, const int* in_sizes, int n_in,
                              void* d_out, int out_size, void* d_ws, size_t ws_size,
                              hipStream_t stream) {
    const float* emb    = (const float*)d_in[0];
    const float* Ws     = (const float*)d_in[1];
    const float* bs     = (const float*)d_in[2];
    const float* gammas = (const float*)d_in[3];
    const float* betas  = (const float*)d_in[4];
    const int*   ei     = (const int*)d_in[5];

    const int N = in_sizes[0] / 127;
    const int E = in_sizes[5] / 2;
    const int* row = ei;
    const int* col = ei + E;
    float* out = (float*)d_out;

    const size_t NH = (size_t)N * 128;
    // bf16 buffers first (keep 16B alignment)
    __hip_bfloat16* XA = (__hip_bfloat16*)d_ws;
    __hip_bfloat16* XB = XA + NH;
    __hip_bfloat16* Wt = XB + NH;           // 3*16384 bf16
    float* deg_src = (float*)(Wt + 3 * 16384);
    float* dinvb   = deg_src + N;
    float* wts     = dinvb + N;
    float* sums    = wts + E;               // 256
    float* ssb     = sums + 256;            // 256
    int*   cnt     = (int*)(ssb + 256);     // N
    int*   cur     = cnt + N;               // N
    int*   srcs    = cur + N;               // E
    int*   blockSums = srcs + E;            // 256
    int*   blockOffs = blockSums + 256;     // 256
    int*   off     = blockOffs + 256;       // N+1
    float* agg     = out;

    const int NH2 = (int)(NH / 2);
    const int PT = (N + 65535) / 65536;
    const int nStripes = (N + 15) / 16;

    hipMemsetAsync(deg_src, 0, sizeof(float) * 2 * (size_t)N, stream);
    wt_kernel<<<(3 * 16384 + 255) / 256, 256, 0, stream>>>(Ws, Wt);
    deg_kernel<<<(E + 255) / 256, 256, 0, stream>>>(row, col, deg_src, dinvb, E);
    dinv_cnt_kernel<<<(N + 255) / 256, 256, 0, stream>>>(dinvb, cnt, N);
    initx_kernel<<<(N * 64 + 255) / 256, 256, 0, stream>>>(emb, deg_src, (unsigned int*)XA, N);
    scan_pass1<<<256, 256, 0, stream>>>(cnt, blockSums, N, PT);
    scan_pass2<<<1, 256, 0, stream>>>(blockSums, blockOffs);
    scan_pass3<<<256, 256, 0, stream>>>(cnt, blockOffs, off, cur, N, PT, E);
    fill_kernel<<<(E + 255) / 256, 256, 0, stream>>>(row, col, dinvb, cur, srcs, wts, E);

    // plumbing: L0: XA -> h(XB) -> XA ; L1: XA -> h(XB) -> XB ; L2: XB -> h(XA) -> out
    const __hip_bfloat16* xin[3]  = {XA, XA, XB};
    __hip_bfloat16*       hbuf[3] = {XB, XB, XA};

    for (int i = 0; i < 3; ++i) {
        gemm_mfma<<<1024, 256, 0, stream>>>(xin[i], Wt + (size_t)i * 16384, hbuf[i], nStripes, N);
        hipMemsetAsync(sums, 0, sizeof(float) * 256, stream);
        gather_kernel<<<2048, 256, 0, stream>>>(hbuf[i], off, srcs, wts, bs + i * 128, agg, sums, N);
        bn_finalize<<<1, 128, 0, stream>>>(sums, gammas + i * 128, betas + i * 128, ssb, N);
        if (i == 0)
            bn_apply<0><<<(NH2 + 255) / 256, 256, 0, stream>>>(agg, ssb, (const unsigned int*)xin[i], (void*)XA, NH2);
        else if (i == 1)
            bn_apply<1><<<(NH2 + 255) / 256, 256, 0, stream>>>(agg, ssb, (const unsigned int*)xin[i], (void*)XB, NH2);
        else
            bn_apply<2><<<(NH2 + 255) / 256, 256, 0, stream>>>(agg, ssb, (const unsigned int*)xin[i], (void*)out, NH2);
    }
}

// Round 5
// 495.459 us; speedup vs baseline: 2.6666x; 1.3058x over previous
//
#include <hip/hip_runtime.h>
#include <hip/hip_bf16.h>
#include <math.h>

#define BN_EPS 1e-5f

typedef __attribute__((ext_vector_type(8))) short short8v;   // 8 x bf16
typedef __attribute__((ext_vector_type(4))) float f32x4;

__device__ inline float bf_lo(unsigned int p) { return __uint_as_float(p << 16); }
__device__ inline float bf_hi(unsigned int p) { return __uint_as_float(p & 0xffff0000u); }
__device__ inline unsigned int packbf(float a, float b) {
    unsigned short lo = __builtin_bit_cast(unsigned short, __float2bfloat16(a));
    unsigned short hi = __builtin_bit_cast(unsigned short, __float2bfloat16(b));
    return (unsigned int)lo | ((unsigned int)hi << 16);
}

// ---------------- degree / feature precompute ----------------

__global__ __launch_bounds__(256) void deg_kernel(const int* __restrict__ row, const int* __restrict__ col,
                                                  float* __restrict__ deg_src, float* __restrict__ deg_dst, int E) {
    int e = blockIdx.x * 256 + threadIdx.x;
    if (e < E) {
        atomicAdd(&deg_src[row[e]], 1.0f);
        atomicAdd(&deg_dst[col[e]], 1.0f);
    }
}

__global__ __launch_bounds__(256) void dinv_cnt_kernel(float* __restrict__ deg_dst, int* __restrict__ cnt, int N) {
    int n = blockIdx.x * 256 + threadIdx.x;
    if (n < N) {
        float d = deg_dst[n];
        cnt[n] = (int)d;
        deg_dst[n] = (d > 0.0f) ? rsqrtf(d) : 0.0f;
    }
}

// x in bf16: thread handles channel pair (2p, 2p+1) of node n
__global__ __launch_bounds__(256) void initx_kernel(const float* __restrict__ emb, const float* __restrict__ deg_src,
                                                    unsigned int* __restrict__ x, int N) {
    int idx = blockIdx.x * 256 + threadIdx.x;   // N*64 pairs
    if (idx < N * 64) {
        int n = idx >> 6, p = idx & 63;
        float v0, v1;
        if (p < 63) {
            v0 = emb[(size_t)n * 127 + 2 * p];
            v1 = emb[(size_t)n * 127 + 2 * p + 1];
        } else {
            v0 = emb[(size_t)n * 127 + 126];
            v1 = logf(deg_src[n] + 1.0f);
        }
        x[idx] = packbf(v0, v1);
    }
}

// W^T in bf16: Wt[l][c][k] = W[l][k][c]
__global__ __launch_bounds__(256) void wt_kernel(const float* __restrict__ Ws, __hip_bfloat16* __restrict__ Wt) {
    int idx = blockIdx.x * 256 + threadIdx.x;
    if (idx < 3 * 16384) {
        int l = idx >> 14, rem = idx & 16383, c = rem >> 7, k = rem & 127;
        Wt[idx] = __float2bfloat16(Ws[(l << 14) + (k << 7) + c]);
    }
}

// ---------------- CSR build: hierarchical exclusive scan + fill ----------------

__global__ __launch_bounds__(256) void scan_pass1(const int* __restrict__ cnt, int* __restrict__ blockSums,
                                                  int N, int PT) {
    __shared__ int lds[256];
    const int tid = threadIdx.x;
    const int start = (blockIdx.x * 256 + tid) * PT;
    int s = 0;
    for (int i = 0; i < PT; ++i) {
        int idx = start + i;
        if (idx < N) s += cnt[idx];
    }
    lds[tid] = s;
    __syncthreads();
    for (int d = 128; d > 0; d >>= 1) {
        if (tid < d) lds[tid] += lds[tid + d];
        __syncthreads();
    }
    if (tid == 0) blockSums[blockIdx.x] = lds[0];
}

__global__ __launch_bounds__(256) void scan_pass2(const int* __restrict__ blockSums, int* __restrict__ blockOffs) {
    __shared__ int lds[256];
    const int tid = threadIdx.x;
    int v = blockSums[tid];
    lds[tid] = v;
    __syncthreads();
    for (int d = 1; d < 256; d <<= 1) {
        int t = (tid >= d) ? lds[tid - d] : 0;
        __syncthreads();
        lds[tid] += t;
        __syncthreads();
    }
    blockOffs[tid] = lds[tid] - v;
}

__global__ __launch_bounds__(256) void scan_pass3(const int* __restrict__ cnt, const int* __restrict__ blockOffs,
                                                  int* __restrict__ off, int* __restrict__ cur,
                                                  int N, int PT, int E) {
    __shared__ int lds[256];
    const int tid = threadIdx.x;
    const int start = (blockIdx.x * 256 + tid) * PT;
    int s = 0;
    for (int i = 0; i < PT; ++i) {
        int idx = start + i;
        if (idx < N) s += cnt[idx];
    }
    lds[tid] = s;
    __syncthreads();
    for (int d = 1; d < 256; d <<= 1) {
        int t = (tid >= d) ? lds[tid - d] : 0;
        __syncthreads();
        lds[tid] += t;
        __syncthreads();
    }
    int prefix = blockOffs[blockIdx.x] + lds[tid] - s;
    for (int i = 0; i < PT; ++i) {
        int idx = start + i;
        if (idx < N) {
            off[idx] = prefix;
            cur[idx] = prefix;
            prefix += cnt[idx];
        }
    }
    if (blockIdx.x == 0 && tid == 0) off[N] = E;
}

__global__ __launch_bounds__(256) void fill_kernel(const int* __restrict__ row, const int* __restrict__ col,
                                                   const float* __restrict__ dinv, int* __restrict__ cur,
                                                   int* __restrict__ srcs, float* __restrict__ wts, int E) {
    int e = blockIdx.x * 256 + threadIdx.x;
    if (e < E) {
        int r = row[e], t = col[e];
        int p = atomicAdd(&cur[t], 1);
        srcs[p] = r;
        wts[p] = dinv[r] * dinv[t];
    }
}

// ---------------- GEMM: H[N,128] = X[N,128] @ W[128,128], bf16 MFMA 16x16x32 ----------------

__global__ __launch_bounds__(256) void gemm_mfma(const __hip_bfloat16* __restrict__ X,
                                                 const __hip_bfloat16* __restrict__ Wt,
                                                 __hip_bfloat16* __restrict__ H, int nStripes, int N) {
    const int lane = threadIdx.x & 63;
    const int wv = threadIdx.x >> 6;
    const int r = lane & 15;
    const int q = lane >> 4;
    const int ch = (blockIdx.x * 4 + wv) & 1;   // stride gridDim*4 is even -> constant per wave

    short8v bfrag[4][4];
#pragma unroll
    for (int ct = 0; ct < 4; ++ct)
#pragma unroll
        for (int kk = 0; kk < 4; ++kk)
            bfrag[ct][kk] = *(const short8v*)(Wt + ((ch * 64 + ct * 16 + r) << 7) + kk * 32 + q * 8);

    const int totalJobs = nStripes * 2;
    for (int job = blockIdx.x * 4 + wv; job < totalJobs; job += gridDim.x * 4) {
        const int s = job >> 1;
        const int arow = s * 16 + r;
        short8v a0 = {}, a1 = {}, a2 = {}, a3 = {};
        if (arow < N) {
            const __hip_bfloat16* xp = X + ((size_t)arow << 7) + q * 8;
            a0 = *(const short8v*)(xp);
            a1 = *(const short8v*)(xp + 32);
            a2 = *(const short8v*)(xp + 64);
            a3 = *(const short8v*)(xp + 96);
        }
        f32x4 acc[4];
#pragma unroll
        for (int ct = 0; ct < 4; ++ct) {
            f32x4 c = {0.f, 0.f, 0.f, 0.f};
            c = __builtin_amdgcn_mfma_f32_16x16x32_bf16(a0, bfrag[ct][0], c, 0, 0, 0);
            c = __builtin_amdgcn_mfma_f32_16x16x32_bf16(a1, bfrag[ct][1], c, 0, 0, 0);
            c = __builtin_amdgcn_mfma_f32_16x16x32_bf16(a2, bfrag[ct][2], c, 0, 0, 0);
            c = __builtin_amdgcn_mfma_f32_16x16x32_bf16(a3, bfrag[ct][3], c, 0, 0, 0);
            acc[ct] = c;
        }
#pragma unroll
        for (int g = 0; g < 4; ++g) {
            int grow = s * 16 + q * 4 + g;
            if (grow < N) {
                __hip_bfloat16* hp = H + ((size_t)grow << 7) + ch * 64 + r;
#pragma unroll
                for (int ct = 0; ct < 4; ++ct)
                    hp[ct * 16] = __float2bfloat16(acc[ct][g]);
            }
        }
    }
}

// ---------------- CSR-vector gather (bf16 h) + bias + fused BN partial stats ----------------
// Wave = 1 node. Lanes = 4 edge-slots (g = lane>>4) x 16 channel-octets (s = lane&15).
// Per iteration: 8 edges (slots g, g+4), each lane loads 16 B (8 channels) of a source row.
// End: shfl_xor(16,32) folds the 4 slots; g==0 lanes own the result.

__global__ __launch_bounds__(256) void gather_kernel(const __hip_bfloat16* __restrict__ h,
                                                     const int* __restrict__ off, const int* __restrict__ srcs,
                                                     const float* __restrict__ wts, const float* __restrict__ bias,
                                                     float* __restrict__ agg, float* __restrict__ sums, int N) {
    __shared__ float sm[2][4][128];
    const int tid = threadIdx.x;
    const int lane = tid & 63;
    const int w = tid >> 6;       // wave 0..3
    const int g = lane >> 4;      // edge slot 0..3
    const int s = lane & 15;      // channel octet: channels 8s..8s+7

    float b8[8];
    *(float4*)&b8[0] = *(const float4*)&bias[s * 8];
    *(float4*)&b8[4] = *(const float4*)&bias[s * 8 + 4];

    float psum[8], psq[8];
#pragma unroll
    for (int j = 0; j < 8; ++j) { psum[j] = 0.f; psq[j] = 0.f; }

    for (int n0 = blockIdx.x * 4 + w; n0 < N; n0 += gridDim.x * 4) {
        const int n = __builtin_amdgcn_readfirstlane(n0);
        const int sOff = off[n], eOff = off[n + 1];
        float acc[8];
#pragma unroll
        for (int j = 0; j < 8; ++j) acc[j] = 0.f;

        for (int i = sOff; i < eOff; i += 8) {
            int i0 = i + g, i1 = i + 4 + g;
            int idx0 = (i0 < eOff) ? i0 : (eOff - 1);
            int idx1 = (i1 < eOff) ? i1 : (eOff - 1);
            float w0 = (i0 < eOff) ? wts[idx0] : 0.0f;
            float w1 = (i1 < eOff) ? wts[idx1] : 0.0f;
            int r0 = srcs[idx0], r1 = srcs[idx1];
            short8v h0 = *(const short8v*)(h + ((size_t)r0 << 7) + s * 8);
            short8v h1 = *(const short8v*)(h + ((size_t)r1 << 7) + s * 8);
#pragma unroll
            for (int j = 0; j < 4; ++j) {
                unsigned int u0 = ((const unsigned int*)&h0)[j];
                unsigned int u1 = ((const unsigned int*)&h1)[j];
                acc[2 * j]     = fmaf(w0, bf_lo(u0), acc[2 * j]);
                acc[2 * j + 1] = fmaf(w0, bf_hi(u0), acc[2 * j + 1]);
                acc[2 * j]     = fmaf(w1, bf_lo(u1), acc[2 * j]);
                acc[2 * j + 1] = fmaf(w1, bf_hi(u1), acc[2 * j + 1]);
            }
        }
        // fold the 4 edge slots; add bias
#pragma unroll
        for (int j = 0; j < 8; ++j) {
            acc[j] += __shfl_xor(acc[j], 16);
            acc[j] += __shfl_xor(acc[j], 32);
            acc[j] += b8[j];
        }
        if (g == 0) {
            float* ap = &agg[((size_t)n << 7) + s * 8];
            *(float4*)ap       = make_float4(acc[0], acc[1], acc[2], acc[3]);
            *(float4*)(ap + 4) = make_float4(acc[4], acc[5], acc[6], acc[7]);
#pragma unroll
            for (int j = 0; j < 8; ++j) {
                psum[j] += acc[j];
                psq[j] = fmaf(acc[j], acc[j], psq[j]);
            }
        }
    }
    if (g == 0) {
#pragma unroll
        for (int j = 0; j < 8; ++j) {
            sm[0][w][s * 8 + j] = psum[j];
            sm[1][w][s * 8 + j] = psq[j];
        }
    }
    __syncthreads();
    if (tid < 128) {
        atomicAdd(&sums[tid], sm[0][0][tid] + sm[0][1][tid] + sm[0][2][tid] + sm[0][3][tid]);
    } else {
        int c = tid - 128;
        atomicAdd(&sums[128 + c], sm[1][0][c] + sm[1][1][c] + sm[1][2][c] + sm[1][3][c]);
    }
}

// ---------------- batchnorm finalize / apply ----------------

__global__ void bn_finalize(const float* __restrict__ sums, const float* __restrict__ gamma,
                            const float* __restrict__ beta, float* __restrict__ ss, int N) {
    int c = threadIdx.x;  // 128 threads
    float mean = sums[c] / (float)N;
    float var  = sums[128 + c] / (float)N - mean * mean;
    float inv  = rsqrtf(fmaxf(var, 0.0f) + BN_EPS);
    float sc   = gamma[c] * inv;
    ss[c]       = sc;
    ss[128 + c] = beta[c] - mean * sc;
}

// MODE 0: bf16 out, no residual; MODE 1: bf16 out + residual; MODE 2: f32 out + residual
template <int MODE>
__global__ __launch_bounds__(256) void bn_apply(const float* __restrict__ agg, const float* __restrict__ ss,
                                                const unsigned int* __restrict__ xprev, void* __restrict__ xout,
                                                int NH2) {
    int idx = blockIdx.x * 256 + threadIdx.x;   // pair index
    if (idx < NH2) {
        int c0 = (idx * 2) & 127;
        float2 v = *(const float2*)&agg[(size_t)idx * 2];
        float r0 = fmaxf(fmaf(v.x, ss[c0],     ss[128 + c0]),     0.0f);
        float r1 = fmaxf(fmaf(v.y, ss[c0 + 1], ss[128 + c0 + 1]), 0.0f);
        if (MODE >= 1) {
            unsigned int xp = xprev[idx];
            r0 = fmaf(0.5f, bf_lo(xp), r0);
            r1 = fmaf(0.5f, bf_hi(xp), r1);
        }
        if (MODE == 2) {
            *(float2*)((float*)xout + (size_t)idx * 2) = make_float2(r0, r1);
        } else {
            ((unsigned int*)xout)[idx] = packbf(r0, r1);
        }
    }
}

// ---------------- launch ----------------

extern "C" void kernel_launch(void* const* d_in, const int* in_sizes, int n_in,
                              void* d_out, int out_size, void* d_ws, size_t ws_size,
                              hipStream_t stream) {
    const float* emb    = (const float*)d_in[0];
    const float* Ws     = (const float*)d_in[1];
    const float* bs     = (const float*)d_in[2];
    const float* gammas = (const float*)d_in[3];
    const float* betas  = (const float*)d_in[4];
    const int*   ei     = (const int*)d_in[5];

    const int N = in_sizes[0] / 127;
    const int E = in_sizes[5] / 2;
    const int* row = ei;
    const int* col = ei + E;
    float* out = (float*)d_out;

    const size_t NH = (size_t)N * 128;
    __hip_bfloat16* XA = (__hip_bfloat16*)d_ws;
    __hip_bfloat16* XB = XA + NH;
    __hip_bfloat16* Wt = XB + NH;           // 3*16384 bf16
    float* deg_src = (float*)(Wt + 3 * 16384);
    float* dinvb   = deg_src + N;
    float* wts     = dinvb + N;
    float* sums    = wts + E;               // 256
    float* ssb     = sums + 256;            // 256
    int*   cnt     = (int*)(ssb + 256);     // N
    int*   cur     = cnt + N;               // N
    int*   srcs    = cur + N;               // E
    int*   blockSums = srcs + E;            // 256
    int*   blockOffs = blockSums + 256;     // 256
    int*   off     = blockOffs + 256;       // N+1
    float* agg     = out;

    const int NH2 = (int)(NH / 2);
    const int PT = (N + 65535) / 65536;
    const int nStripes = (N + 15) / 16;

    hipMemsetAsync(deg_src, 0, sizeof(float) * 2 * (size_t)N, stream);
    wt_kernel<<<(3 * 16384 + 255) / 256, 256, 0, stream>>>(Ws, Wt);
    deg_kernel<<<(E + 255) / 256, 256, 0, stream>>>(row, col, deg_src, dinvb, E);
    dinv_cnt_kernel<<<(N + 255) / 256, 256, 0, stream>>>(dinvb, cnt, N);
    initx_kernel<<<(N * 64 + 255) / 256, 256, 0, stream>>>(emb, deg_src, (unsigned int*)XA, N);
    scan_pass1<<<256, 256, 0, stream>>>(cnt, blockSums, N, PT);
    scan_pass2<<<1, 256, 0, stream>>>(blockSums, blockOffs);
    scan_pass3<<<256, 256, 0, stream>>>(cnt, blockOffs, off, cur, N, PT, E);
    fill_kernel<<<(E + 255) / 256, 256, 0, stream>>>(row, col, dinvb, cur, srcs, wts, E);

    // plumbing: L0: XA -> h(XB) -> XA ; L1: XA -> h(XB) -> XB ; L2: XB -> h(XA) -> out
    const __hip_bfloat16* xin[3]  = {XA, XA, XB};
    __hip_bfloat16*       hbuf[3] = {XB, XB, XA};

    for (int i = 0; i < 3; ++i) {
        gemm_mfma<<<1024, 256, 0, stream>>>(xin[i], Wt + (size_t)i * 16384, hbuf[i], nStripes, N);
        hipMemsetAsync(sums, 0, sizeof(float) * 256, stream);
        gather_kernel<<<2048, 256, 0, stream>>>(hbuf[i], off, srcs, wts, bs + i * 128, agg, sums, N);
        bn_finalize<<<1, 128, 0, stream>>>(sums, gammas + i * 128, betas + i * 128, ssb, N);
        if (i == 0)
            bn_apply<0><<<(NH2 + 255) / 256, 256, 0, stream>>>(agg, ssb, (const unsigned int*)xin[i], (void*)XA, NH2);
        else if (i == 1)
            bn_apply<1><<<(NH2 + 255) / 256, 256, 0, stream>>>(agg, ssb, (const unsigned int*)xin[i], (void*)XB, NH2);
        else
            bn_apply<2><<<(NH2 + 255) / 256, 256, 0, stream>>>(agg, ssb, (const unsigned int*)xin[i], (void*)out, NH2);
    }
}

// Round 6
// 445.737 us; speedup vs baseline: 2.9641x; 1.1115x over previous
//
#include <hip/hip_runtime.h>
#include <hip/hip_bf16.h>
#include <math.h>

#define BN_EPS 1e-5f

typedef __attribute__((ext_vector_type(8))) short short8v;   // 8 x bf16
typedef __attribute__((ext_vector_type(4))) float f32x4;

__device__ inline float bf_lo(unsigned int p) { return __uint_as_float(p << 16); }
__device__ inline float bf_hi(unsigned int p) { return __uint_as_float(p & 0xffff0000u); }
__device__ inline unsigned int packbf(float a, float b) {
    unsigned short lo = __builtin_bit_cast(unsigned short, __float2bfloat16(a));
    unsigned short hi = __builtin_bit_cast(unsigned short, __float2bfloat16(b));
    return (unsigned int)lo | ((unsigned int)hi << 16);
}

// ---------------- degree / feature precompute ----------------

__global__ __launch_bounds__(256) void deg_kernel(const int* __restrict__ row, const int* __restrict__ col,
                                                  float* __restrict__ deg_src, float* __restrict__ deg_dst, int E) {
    int e = blockIdx.x * 256 + threadIdx.x;
    if (e < E) {
        atomicAdd(&deg_src[row[e]], 1.0f);
        atomicAdd(&deg_dst[col[e]], 1.0f);
    }
}

__global__ __launch_bounds__(256) void dinv_cnt_kernel(float* __restrict__ deg_dst, int* __restrict__ cnt, int N) {
    int n = blockIdx.x * 256 + threadIdx.x;
    if (n < N) {
        float d = deg_dst[n];
        cnt[n] = (int)d;
        deg_dst[n] = (d > 0.0f) ? rsqrtf(d) : 0.0f;
    }
}

// x in bf16: thread handles channel pair (2p, 2p+1) of node n
__global__ __launch_bounds__(256) void initx_kernel(const float* __restrict__ emb, const float* __restrict__ deg_src,
                                                    unsigned int* __restrict__ x, int N) {
    int idx = blockIdx.x * 256 + threadIdx.x;   // N*64 pairs
    if (idx < N * 64) {
        int n = idx >> 6, p = idx & 63;
        float v0, v1;
        if (p < 63) {
            v0 = emb[(size_t)n * 127 + 2 * p];
            v1 = emb[(size_t)n * 127 + 2 * p + 1];
        } else {
            v0 = emb[(size_t)n * 127 + 126];
            v1 = logf(deg_src[n] + 1.0f);
        }
        x[idx] = packbf(v0, v1);
    }
}

// W^T in bf16: Wt[l][c][k] = W[l][k][c]
__global__ __launch_bounds__(256) void wt_kernel(const float* __restrict__ Ws, __hip_bfloat16* __restrict__ Wt) {
    int idx = blockIdx.x * 256 + threadIdx.x;
    if (idx < 3 * 16384) {
        int l = idx >> 14, rem = idx & 16383, c = rem >> 7, k = rem & 127;
        Wt[idx] = __float2bfloat16(Ws[(l << 14) + (k << 7) + c]);
    }
}

// ---------------- CSR build: hierarchical exclusive scan + fill ----------------

__global__ __launch_bounds__(256) void scan_pass1(const int* __restrict__ cnt, int* __restrict__ blockSums,
                                                  int N, int PT) {
    __shared__ int lds[256];
    const int tid = threadIdx.x;
    const int start = (blockIdx.x * 256 + tid) * PT;
    int s = 0;
    for (int i = 0; i < PT; ++i) {
        int idx = start + i;
        if (idx < N) s += cnt[idx];
    }
    lds[tid] = s;
    __syncthreads();
    for (int d = 128; d > 0; d >>= 1) {
        if (tid < d) lds[tid] += lds[tid + d];
        __syncthreads();
    }
    if (tid == 0) blockSums[blockIdx.x] = lds[0];
}

__global__ __launch_bounds__(256) void scan_pass2(const int* __restrict__ blockSums, int* __restrict__ blockOffs) {
    __shared__ int lds[256];
    const int tid = threadIdx.x;
    int v = blockSums[tid];
    lds[tid] = v;
    __syncthreads();
    for (int d = 1; d < 256; d <<= 1) {
        int t = (tid >= d) ? lds[tid - d] : 0;
        __syncthreads();
        lds[tid] += t;
        __syncthreads();
    }
    blockOffs[tid] = lds[tid] - v;
}

__global__ __launch_bounds__(256) void scan_pass3(const int* __restrict__ cnt, const int* __restrict__ blockOffs,
                                                  int* __restrict__ off, int* __restrict__ cur,
                                                  int N, int PT, int E) {
    __shared__ int lds[256];
    const int tid = threadIdx.x;
    const int start = (blockIdx.x * 256 + tid) * PT;
    int s = 0;
    for (int i = 0; i < PT; ++i) {
        int idx = start + i;
        if (idx < N) s += cnt[idx];
    }
    lds[tid] = s;
    __syncthreads();
    for (int d = 1; d < 256; d <<= 1) {
        int t = (tid >= d) ? lds[tid - d] : 0;
        __syncthreads();
        lds[tid] += t;
        __syncthreads();
    }
    int prefix = blockOffs[blockIdx.x] + lds[tid] - s;
    for (int i = 0; i < PT; ++i) {
        int idx = start + i;
        if (idx < N) {
            off[idx] = prefix;
            cur[idx] = prefix;
            prefix += cnt[idx];
        }
    }
    if (blockIdx.x == 0 && tid == 0) off[N] = E;
}

// meta[p] = (src, bitcast(weight)) — one 8B load per edge later
__global__ __launch_bounds__(256) void fill_kernel(const int* __restrict__ row, const int* __restrict__ col,
                                                   const float* __restrict__ dinv, int* __restrict__ cur,
                                                   int2* __restrict__ meta, int E) {
    int e = blockIdx.x * 256 + threadIdx.x;
    if (e < E) {
        int r = row[e], t = col[e];
        int p = atomicAdd(&cur[t], 1);
        meta[p] = make_int2(r, __float_as_int(dinv[r] * dinv[t]));
    }
}

// ---------------- GEMM: H[N,128] = X[N,128] @ W[128,128], bf16 MFMA 16x16x32 ----------------
// block 0 also zeroes the BN sums accumulator for the following gather.

__global__ __launch_bounds__(256) void gemm_mfma(const __hip_bfloat16* __restrict__ X,
                                                 const __hip_bfloat16* __restrict__ Wt,
                                                 __hip_bfloat16* __restrict__ H, float* __restrict__ sums,
                                                 int nStripes, int N) {
    if (blockIdx.x == 0) sums[threadIdx.x] = 0.0f;   // 256 threads cover 256 floats

    const int lane = threadIdx.x & 63;
    const int wv = threadIdx.x >> 6;
    const int r = lane & 15;
    const int q = lane >> 4;
    const int ch = (blockIdx.x * 4 + wv) & 1;   // stride gridDim*4 is even -> constant per wave

    short8v bfrag[4][4];
#pragma unroll
    for (int ct = 0; ct < 4; ++ct)
#pragma unroll
        for (int kk = 0; kk < 4; ++kk)
            bfrag[ct][kk] = *(const short8v*)(Wt + ((ch * 64 + ct * 16 + r) << 7) + kk * 32 + q * 8);

    const int totalJobs = nStripes * 2;
    for (int job = blockIdx.x * 4 + wv; job < totalJobs; job += gridDim.x * 4) {
        const int s = job >> 1;
        const int arow = s * 16 + r;
        short8v a0 = {}, a1 = {}, a2 = {}, a3 = {};
        if (arow < N) {
            const __hip_bfloat16* xp = X + ((size_t)arow << 7) + q * 8;
            a0 = *(const short8v*)(xp);
            a1 = *(const short8v*)(xp + 32);
            a2 = *(const short8v*)(xp + 64);
            a3 = *(const short8v*)(xp + 96);
        }
        f32x4 acc[4];
#pragma unroll
        for (int ct = 0; ct < 4; ++ct) {
            f32x4 c = {0.f, 0.f, 0.f, 0.f};
            c = __builtin_amdgcn_mfma_f32_16x16x32_bf16(a0, bfrag[ct][0], c, 0, 0, 0);
            c = __builtin_amdgcn_mfma_f32_16x16x32_bf16(a1, bfrag[ct][1], c, 0, 0, 0);
            c = __builtin_amdgcn_mfma_f32_16x16x32_bf16(a2, bfrag[ct][2], c, 0, 0, 0);
            c = __builtin_amdgcn_mfma_f32_16x16x32_bf16(a3, bfrag[ct][3], c, 0, 0, 0);
            acc[ct] = c;
        }
#pragma unroll
        for (int g = 0; g < 4; ++g) {
            int grow = s * 16 + q * 4 + g;
            if (grow < N) {
                __hip_bfloat16* hp = H + ((size_t)grow << 7) + ch * 64 + r;
#pragma unroll
                for (int ct = 0; ct < 4; ++ct)
                    hp[ct * 16] = __float2bfloat16(acc[ct][g]);
            }
        }
    }
}

// ---------------- dual-node CSR-vector gather + bias + fused BN partial stats ----------------
// Wave = 2 adjacent nodes (A,B), each with 4 edge-slots (g) x 16 channel-octets (s).
// Per iteration: 8 edges per node, 4 independent 16B h-loads in flight.
// Inactive slots clamp to edge 0 with weight 0 (L2-hot line, branchless).

__global__ __launch_bounds__(256) void gather_kernel(const __hip_bfloat16* __restrict__ h,
                                                     const int* __restrict__ off, const int2* __restrict__ meta,
                                                     const float* __restrict__ bias,
                                                     unsigned int* __restrict__ aggb, float* __restrict__ sums, int N) {
    __shared__ float sm[2][4][128];
    const int tid = threadIdx.x;
    const int lane = tid & 63;
    const int w = tid >> 6;       // wave 0..3
    const int g = lane >> 4;      // edge slot 0..3
    const int s = lane & 15;      // channel octet: channels 8s..8s+7

    float b8[8];
    *(float4*)&b8[0] = *(const float4*)&bias[s * 8];
    *(float4*)&b8[4] = *(const float4*)&bias[s * 8 + 4];

    float psum[8], psq[8];
#pragma unroll
    for (int j = 0; j < 8; ++j) { psum[j] = 0.f; psq[j] = 0.f; }

    for (int base = (blockIdx.x * 4 + w) * 2; base < N; base += gridDim.x * 8) {
        const int nA = __builtin_amdgcn_readfirstlane(base);
        const int hasB = (nA + 1 < N);
        const int sA = off[nA];
        const int eA = off[nA + 1];
        const int eB = hasB ? off[nA + 2] : eA;

        float accA[8], accB[8];
#pragma unroll
        for (int j = 0; j < 8; ++j) { accA[j] = 0.f; accB[j] = 0.f; }

        int iA = sA, iB = eA;   // B's segment starts where A's ends
        while (iA < eA || iB < eB) {
            int i0A = iA + g, i1A = iA + 4 + g;
            int i0B = iB + g, i1B = iB + 4 + g;
            int idx0A = (i0A < eA) ? i0A : 0;
            int idx1A = (i1A < eA) ? i1A : 0;
            int idx0B = (i0B < eB) ? i0B : 0;
            int idx1B = (i1B < eB) ? i1B : 0;
            int2 m0A = meta[idx0A], m1A = meta[idx1A];
            int2 m0B = meta[idx0B], m1B = meta[idx1B];
            float w0A = (i0A < eA) ? __int_as_float(m0A.y) : 0.f;
            float w1A = (i1A < eA) ? __int_as_float(m1A.y) : 0.f;
            float w0B = (i0B < eB) ? __int_as_float(m0B.y) : 0.f;
            float w1B = (i1B < eB) ? __int_as_float(m1B.y) : 0.f;
            short8v h0A = *(const short8v*)(h + ((size_t)m0A.x << 7) + s * 8);
            short8v h1A = *(const short8v*)(h + ((size_t)m1A.x << 7) + s * 8);
            short8v h0B = *(const short8v*)(h + ((size_t)m0B.x << 7) + s * 8);
            short8v h1B = *(const short8v*)(h + ((size_t)m1B.x << 7) + s * 8);
#pragma unroll
            for (int j = 0; j < 4; ++j) {
                unsigned int u;
                u = ((const unsigned int*)&h0A)[j];
                accA[2 * j]     = fmaf(w0A, bf_lo(u), accA[2 * j]);
                accA[2 * j + 1] = fmaf(w0A, bf_hi(u), accA[2 * j + 1]);
                u = ((const unsigned int*)&h1A)[j];
                accA[2 * j]     = fmaf(w1A, bf_lo(u), accA[2 * j]);
                accA[2 * j + 1] = fmaf(w1A, bf_hi(u), accA[2 * j + 1]);
                u = ((const unsigned int*)&h0B)[j];
                accB[2 * j]     = fmaf(w0B, bf_lo(u), accB[2 * j]);
                accB[2 * j + 1] = fmaf(w0B, bf_hi(u), accB[2 * j + 1]);
                u = ((const unsigned int*)&h1B)[j];
                accB[2 * j]     = fmaf(w1B, bf_lo(u), accB[2 * j]);
                accB[2 * j + 1] = fmaf(w1B, bf_hi(u), accB[2 * j + 1]);
            }
            iA += 8; iB += 8;
        }
        // fold the 4 edge slots; add bias (all lanes end with full sums)
#pragma unroll
        for (int j = 0; j < 8; ++j) {
            accA[j] += __shfl_xor(accA[j], 16);
            accA[j] += __shfl_xor(accA[j], 32);
            accA[j] += b8[j];
            accB[j] += __shfl_xor(accB[j], 16);
            accB[j] += __shfl_xor(accB[j], 32);
            accB[j] += b8[j];
        }
        if (g == 0) {
            unsigned int pk[4];
#pragma unroll
            for (int j = 0; j < 4; ++j) pk[j] = packbf(accA[2 * j], accA[2 * j + 1]);
            *(uint4*)(aggb + ((size_t)nA << 6) + s * 4) = *(uint4*)pk;
#pragma unroll
            for (int j = 0; j < 8; ++j) {
                psum[j] += accA[j];
                psq[j] = fmaf(accA[j], accA[j], psq[j]);
            }
            if (hasB) {
#pragma unroll
                for (int j = 0; j < 8; ++j) {
                    psum[j] += accB[j];
                    psq[j] = fmaf(accB[j], accB[j], psq[j]);
                }
            }
        } else if (g == 1 && hasB) {
            unsigned int pk[4];
#pragma unroll
            for (int j = 0; j < 4; ++j) pk[j] = packbf(accB[2 * j], accB[2 * j + 1]);
            *(uint4*)(aggb + ((size_t)(nA + 1) << 6) + s * 4) = *(uint4*)pk;
        }
    }
    if (g == 0) {
#pragma unroll
        for (int j = 0; j < 8; ++j) {
            sm[0][w][s * 8 + j] = psum[j];
            sm[1][w][s * 8 + j] = psq[j];
        }
    }
    __syncthreads();
    if (tid < 128) {
        atomicAdd(&sums[tid], sm[0][0][tid] + sm[0][1][tid] + sm[0][2][tid] + sm[0][3][tid]);
    } else {
        int c = tid - 128;
        atomicAdd(&sums[128 + c], sm[1][0][c] + sm[1][1][c] + sm[1][2][c] + sm[1][3][c]);
    }
}

// ---------------- batchnorm apply (finalize inlined; bf16 agg in) ----------------
// thread = 8 channels (one octet). MODE 0: bf16 out; 1: bf16 out + residual; 2: f32 out + residual.

template <int MODE>
__global__ __launch_bounds__(256) void bn_apply(const uint4* __restrict__ aggb, const float* __restrict__ sums,
                                                const float* __restrict__ gamma, const float* __restrict__ beta,
                                                const uint4* __restrict__ xprev, void* __restrict__ xout,
                                                int NO, float invN) {
    int idx = blockIdx.x * 256 + threadIdx.x;
    if (idx >= NO) return;
    const int c0 = (idx & 15) * 8;

    float su[8], sq[8], gm[8], bt[8];
    *(float4*)&su[0] = *(const float4*)&sums[c0];
    *(float4*)&su[4] = *(const float4*)&sums[c0 + 4];
    *(float4*)&sq[0] = *(const float4*)&sums[128 + c0];
    *(float4*)&sq[4] = *(const float4*)&sums[128 + c0 + 4];
    *(float4*)&gm[0] = *(const float4*)&gamma[c0];
    *(float4*)&gm[4] = *(const float4*)&gamma[c0 + 4];
    *(float4*)&bt[0] = *(const float4*)&beta[c0];
    *(float4*)&bt[4] = *(const float4*)&beta[c0 + 4];

    float sc[8], sh[8];
#pragma unroll
    for (int j = 0; j < 8; ++j) {
        float m = su[j] * invN;
        float v = sq[j] * invN - m * m;
        float inv = rsqrtf(fmaxf(v, 0.0f) + BN_EPS);
        sc[j] = gm[j] * inv;
        sh[j] = bt[j] - m * sc[j];
    }

    uint4 av = aggb[idx];
    const unsigned int* au = (const unsigned int*)&av;
    float r[8];
#pragma unroll
    for (int j = 0; j < 4; ++j) {
        r[2 * j]     = fmaxf(fmaf(bf_lo(au[j]), sc[2 * j],     sh[2 * j]),     0.f);
        r[2 * j + 1] = fmaxf(fmaf(bf_hi(au[j]), sc[2 * j + 1], sh[2 * j + 1]), 0.f);
    }
    if (MODE >= 1) {
        uint4 xv = xprev[idx];
        const unsigned int* xu = (const unsigned int*)&xv;
#pragma unroll
        for (int j = 0; j < 4; ++j) {
            r[2 * j]     = fmaf(0.5f, bf_lo(xu[j]), r[2 * j]);
            r[2 * j + 1] = fmaf(0.5f, bf_hi(xu[j]), r[2 * j + 1]);
        }
    }
    if (MODE == 2) {
        float* op = (float*)xout + (size_t)idx * 8;
        *(float4*)op       = make_float4(r[0], r[1], r[2], r[3]);
        *(float4*)(op + 4) = make_float4(r[4], r[5], r[6], r[7]);
    } else {
        unsigned int pk[4];
#pragma unroll
        for (int j = 0; j < 4; ++j) pk[j] = packbf(r[2 * j], r[2 * j + 1]);
        ((uint4*)xout)[idx] = *(uint4*)pk;
    }
}

// ---------------- launch ----------------

extern "C" void kernel_launch(void* const* d_in, const int* in_sizes, int n_in,
                              void* d_out, int out_size, void* d_ws, size_t ws_size,
                              hipStream_t stream) {
    const float* emb    = (const float*)d_in[0];
    const float* Ws     = (const float*)d_in[1];
    const float* bs     = (const float*)d_in[2];
    const float* gammas = (const float*)d_in[3];
    const float* betas  = (const float*)d_in[4];
    const int*   ei     = (const int*)d_in[5];

    const int N = in_sizes[0] / 127;
    const int E = in_sizes[5] / 2;
    const int* row = ei;
    const int* col = ei + E;
    float* out = (float*)d_out;

    const size_t NH = (size_t)N * 128;
    __hip_bfloat16* XA = (__hip_bfloat16*)d_ws;
    __hip_bfloat16* XB = XA + NH;
    unsigned int*  AGG = (unsigned int*)(XB + NH);      // NH/2 uints (bf16 pairs)
    int2*         meta = (int2*)(AGG + NH / 2);         // E
    __hip_bfloat16* Wt = (__hip_bfloat16*)(meta + E);   // 3*16384
    float* deg_src = (float*)(Wt + 3 * 16384);          // N
    float* dinvb   = deg_src + N;                       // N
    float* sums    = dinvb + N;                         // 256
    int*   cnt     = (int*)(sums + 256);                // N
    int*   cur     = cnt + N;                           // N
    int*   blockSums = cur + N;                         // 256
    int*   blockOffs = blockSums + 256;                 // 256
    int*   off     = blockOffs + 256;                   // N+1

    const int NO = (int)(NH / 8);          // octets
    const int PT = (N + 65535) / 65536;
    const int nStripes = (N + 15) / 16;
    const float invN = 1.0f / (float)N;

    hipMemsetAsync(deg_src, 0, sizeof(float) * 2 * (size_t)N, stream);
    wt_kernel<<<(3 * 16384 + 255) / 256, 256, 0, stream>>>(Ws, Wt);
    deg_kernel<<<(E + 255) / 256, 256, 0, stream>>>(row, col, deg_src, dinvb, E);
    dinv_cnt_kernel<<<(N + 255) / 256, 256, 0, stream>>>(dinvb, cnt, N);
    initx_kernel<<<(N * 64 + 255) / 256, 256, 0, stream>>>(emb, deg_src, (unsigned int*)XA, N);
    scan_pass1<<<256, 256, 0, stream>>>(cnt, blockSums, N, PT);
    scan_pass2<<<1, 256, 0, stream>>>(blockSums, blockOffs);
    scan_pass3<<<256, 256, 0, stream>>>(cnt, blockOffs, off, cur, N, PT, E);
    fill_kernel<<<(E + 255) / 256, 256, 0, stream>>>(row, col, dinvb, cur, meta, E);

    // plumbing: L0: XA -> h(XB) -> x(XA) ; L1: XA -> h(XB) -> x(XB) ; L2: XB -> h(XA) -> out
    const __hip_bfloat16* xin[3]  = {XA, XA, XB};
    __hip_bfloat16*       hbuf[3] = {XB, XB, XA};

    for (int i = 0; i < 3; ++i) {
        gemm_mfma<<<1024, 256, 0, stream>>>(xin[i], Wt + (size_t)i * 16384, hbuf[i], sums, nStripes, N);
        gather_kernel<<<2048, 256, 0, stream>>>(hbuf[i], off, meta, bs + i * 128, AGG, sums, N);
        if (i == 0)
            bn_apply<0><<<(NO + 255) / 256, 256, 0, stream>>>((const uint4*)AGG, sums, gammas, betas,
                                                              (const uint4*)xin[i], (void*)XA, NO, invN);
        else if (i == 1)
            bn_apply<1><<<(NO + 255) / 256, 256, 0, stream>>>((const uint4*)AGG, sums, gammas + 128, betas + 128,
                                                              (const uint4*)xin[i], (void*)XB, NO, invN);
        else
            bn_apply<2><<<(NO + 255) / 256, 256, 0, stream>>>((const uint4*)AGG, sums, gammas + 256, betas + 256,
                                                              (const uint4*)xin[i], (void*)out, NO, invN);
    }
}